// Round 4
// baseline (12775.971 us; speedup 1.0000x reference)
//
#include <hip/hip_runtime.h>
#include <hip/hip_bf16.h>
#include <hip/hip_cooperative_groups.h>
#include <math.h>

namespace cg = cooperative_groups;

#define Bb 64
#define Tt 512
#define Ii 1024
#define Hh 2048

typedef __attribute__((ext_vector_type(8))) short bf16x8;
typedef __attribute__((ext_vector_type(8))) unsigned short ushort8;
typedef __attribute__((ext_vector_type(4))) float f32x4;

__device__ __forceinline__ unsigned short f2bf(float x) {
    unsigned int u = __float_as_uint(x);
    unsigned int r = u + 0x7fffu + ((u >> 16) & 1u);
    return (unsigned short)(r >> 16);
}

// ---------------------------------------------------------------------------
// Convert fp32 -> bf16 (raw ushort bits), 4 elems/thread.
// ---------------------------------------------------------------------------
__global__ __launch_bounds__(256) void cvt_kernel(
    const float* __restrict__ src, unsigned short* __restrict__ dst)
{
    const int i = (blockIdx.x * 256 + threadIdx.x) * 4;
    float4 v = *(const float4*)(src + i);
    ushort4 o;
    o.x = f2bf(v.x); o.y = f2bf(v.y); o.z = f2bf(v.z); o.w = f2bf(v.w);
    *(ushort4*)(dst + i) = o;
}

// ---------------------------------------------------------------------------
// xproj: out[M=B*T][N=H] = input[M][K=I] @ w_ih^T + b_ih   (bf16 MFMA)
// 128x128 tile, BK=32, 4 waves (2x2 quadrants of 64x64), 16x16x32 MFMA.
// ---------------------------------------------------------------------------
__global__ __launch_bounds__(256, 2) void xproj_kernel(
    const float* __restrict__ A,              // input [32768][1024] fp32
    const unsigned short* __restrict__ Wbf,   // w_ih bf16 [2048][1024]
    const float* __restrict__ bias,           // b_ih [2048]
    float* __restrict__ out)                  // [32768][2048] fp32
{
    __shared__ unsigned short As[128 * 40];
    __shared__ unsigned short Bs[128 * 40];

    const int tid  = threadIdx.x;
    const int lane = tid & 63;
    const int wid  = tid >> 6;
    const int wm   = wid & 1;
    const int wn   = wid >> 1;
    const int rlo  = lane & 15;
    const int khi  = lane >> 4;

    const int m0 = blockIdx.y * 128;
    const int n0 = blockIdx.x * 128;

    f32x4 acc[4][4];
    #pragma unroll
    for (int i = 0; i < 4; ++i)
        #pragma unroll
        for (int j = 0; j < 4; ++j) acc[i][j] = (f32x4)0.f;

    for (int k0 = 0; k0 < Ii; k0 += 32) {
        #pragma unroll
        for (int p = 0; p < 4; ++p) {
            const int flat = p * 256 + tid;
            const int row  = flat >> 3;
            const int c4   = flat & 7;
            float4 v = *(const float4*)(A + (size_t)(m0 + row) * Ii + k0 + c4 * 4);
            ushort4 o;
            o.x = f2bf(v.x); o.y = f2bf(v.y); o.z = f2bf(v.z); o.w = f2bf(v.w);
            *(ushort4*)(As + row * 40 + c4 * 4) = o;
        }
        #pragma unroll
        for (int p = 0; p < 2; ++p) {
            const int flat = p * 256 + tid;
            const int row  = flat >> 2;
            const int c8   = flat & 3;
            ushort8 v = *(const ushort8*)(Wbf + (size_t)(n0 + row) * Ii + k0 + c8 * 8);
            *(ushort8*)(Bs + row * 40 + c8 * 8) = v;
        }
        __syncthreads();

        bf16x8 af[4], bfr[4];
        #pragma unroll
        for (int i = 0; i < 4; ++i)
            af[i] = *(const bf16x8*)(As + (wm * 64 + i * 16 + rlo) * 40 + khi * 8);
        #pragma unroll
        for (int j = 0; j < 4; ++j)
            bfr[j] = *(const bf16x8*)(Bs + (wn * 64 + j * 16 + rlo) * 40 + khi * 8);
        #pragma unroll
        for (int i = 0; i < 4; ++i)
            #pragma unroll
            for (int j = 0; j < 4; ++j)
                acc[i][j] = __builtin_amdgcn_mfma_f32_16x16x32_bf16(
                    af[i], bfr[j], acc[i][j], 0, 0, 0);
        __syncthreads();
    }

    #pragma unroll
    for (int j = 0; j < 4; ++j) {
        const int col = n0 + wn * 64 + j * 16 + rlo;
        const float bj = bias[col];
        #pragma unroll
        for (int i = 0; i < 4; ++i) {
            #pragma unroll
            for (int r = 0; r < 4; ++r) {
                const int m = m0 + wm * 64 + i * 16 + khi * 4 + r;
                out[(size_t)m * Hh + col] = acc[i][j][r] + bj;
            }
        }
    }
}

// ---------------------------------------------------------------------------
// Persistent recurrence kernel: all 512 steps with grid.sync() between.
// Grid: 64 WGs x 512 threads (8 waves). WG owns 32 cols (blk*32..+31).
// Wave wid: ks = wid&3 -> K-slice [ks*512, +512); nh = wid>>2 -> col half.
// w_hh slice (16 cols x 512 K) held in 16 bf16x8 VGPR frags for ALL steps.
// Per step: 4 mtiles x 16 kit MFMA over L2-resident h ping-pong buffer,
// 4-way k-split LDS reduce, fused tanh epilogue (xp prefetched), grid sync.
// ---------------------------------------------------------------------------
__global__ __launch_bounds__(512, 2) void rnn_persistent(
    const unsigned short* __restrict__ w_bf,   // [2048][2048] bf16
    unsigned short* __restrict__ h_bf,         // [2][64][2048] bf16 ping-pong
    const float* __restrict__ b_hh,            // [2048]
    const float* __restrict__ internal,        // [64][512]
    float* __restrict__ out)                   // [B][T][H] ++ [B][H]
{
    cg::grid_group grid = cg::this_grid();

    __shared__ f32x4 red[4][2][4][64];   // [ks][nh][mtile][lane] = 32 KiB

    const int tid  = threadIdx.x;
    const int lane = tid & 63;
    const int wid  = tid >> 6;           // 0..7
    const int ks   = wid & 3;            // K-slice
    const int nh   = wid >> 2;           // col half
    const int rlo  = lane & 15;
    const int khi  = lane >> 4;
    const int blk  = blockIdx.x;         // 0..63

    // ---- preload this wave's w_hh slice into registers (stays all 512 steps)
    const int wcol = blk * 32 + nh * 16 + rlo;
    bf16x8 wf[16];
    {
        const unsigned short* wrow = w_bf + (size_t)wcol * Hh + ks * 512 + khi * 8;
        #pragma unroll
        for (int kit = 0; kit < 16; ++kit)
            wf[kit] = *(const bf16x8*)(wrow + kit * 32);
    }

    // ---- epilogue fixed indices: thread finalizes rows {rq, rq+16, rq+32, rq+48}
    // of column colg.  (row = e*16 + rq; m=e, khi_e=rq>>2, r=rq&3)
    const int c5   = tid & 31;
    const int enh  = c5 >> 4;
    const int erlo = c5 & 15;
    const int rq   = tid >> 5;           // 0..15
    const int ekhi = rq >> 2;
    const int er   = rq & 3;
    const int colg = blk * 32 + c5;
    const float bh = b_hh[colg];

    for (int t = 0; t < Tt; ++t) {
        const unsigned short* h_cur = h_bf + (size_t)(t & 1) * Bb * Hh;
        unsigned short*       h_nxt = h_bf + (size_t)((t + 1) & 1) * Bb * Hh;

        // prefetch epilogue operands (independent of h -> hides under MFMA)
        float xp[4], nz[4];
        #pragma unroll
        for (int e = 0; e < 4; ++e) {
            const int row = e * 16 + rq;
            xp[e] = out[(size_t)row * Tt * Hh + (size_t)t * Hh + colg];
            nz[e] = internal[row * Tt + t];
        }

        // ---- GEMM: this wave's K-slice for its 16 cols x all 64 batches
        f32x4 acc[4];
        #pragma unroll
        for (int m = 0; m < 4; ++m) acc[m] = (f32x4)0.f;

        const unsigned short* hrow = h_cur + (size_t)rlo * Hh + ks * 512 + khi * 8;
        #pragma unroll
        for (int kit = 0; kit < 16; ++kit) {
            #pragma unroll
            for (int m = 0; m < 4; ++m) {
                bf16x8 av = *(const bf16x8*)(hrow + (size_t)(m * 16) * Hh + kit * 32);
                acc[m] = __builtin_amdgcn_mfma_f32_16x16x32_bf16(av, wf[kit], acc[m], 0, 0, 0);
            }
        }

        // ---- k-split reduce through LDS
        #pragma unroll
        for (int m = 0; m < 4; ++m)
            red[ks][nh][m][lane] = acc[m];
        __syncthreads();

        #pragma unroll
        for (int e = 0; e < 4; ++e) {
            float s = 0.f;
            #pragma unroll
            for (int kks = 0; kks < 4; ++kks)
                s += red[kks][enh][e][ekhi * 16 + erlo][er];
            const float g = tanhf(xp[e] + nz[e] + bh + s);
            const int row = e * 16 + rq;
            out[(size_t)row * Tt * Hh + (size_t)t * Hh + colg] = g;
            h_nxt[(size_t)row * Hh + colg] = f2bf(g);
            if (t == Tt - 1)
                out[(size_t)Bb * Tt * Hh + (size_t)row * Hh + colg] = g;
        }

        // one barrier per step: h_nxt visible device-wide, red safe to reuse
        grid.sync();
    }
}

// ---------------------------------------------------------------------------
extern "C" void kernel_launch(void* const* d_in, const int* in_sizes, int n_in,
                              void* d_out, int out_size, void* d_ws, size_t ws_size,
                              hipStream_t stream) {
    const float* input    = (const float*)d_in[0];
    const float* internal = (const float*)d_in[1];
    const float* w_ih     = (const float*)d_in[2];
    const float* w_hh     = (const float*)d_in[3];
    const float* b_ih     = (const float*)d_in[4];
    const float* b_hh     = (const float*)d_in[5];
    const float* h0       = (const float*)d_in[6];
    float* out = (float*)d_out;

    // ws layout: w_hh_bf [4M ushort] | w_ih_bf [2M ushort] | h_bf[2][64][2048]
    unsigned short* w_hh_bf = (unsigned short*)d_ws;
    unsigned short* w_ih_bf = w_hh_bf + (size_t)Hh * Hh;
    unsigned short* h_bf    = w_ih_bf + (size_t)Hh * Ii;

    hipLaunchKernelGGL(cvt_kernel, dim3((Hh * Hh) / 1024), dim3(256), 0, stream,
                       w_hh, w_hh_bf);
    hipLaunchKernelGGL(cvt_kernel, dim3((Hh * Ii) / 1024), dim3(256), 0, stream,
                       w_ih, w_ih_bf);
    hipLaunchKernelGGL(cvt_kernel, dim3((Bb * Hh) / 1024), dim3(256), 0, stream,
                       h0, h_bf);

    dim3 g1(Hh / 128, (Bb * Tt) / 128);   // 16 x 256
    hipLaunchKernelGGL(xproj_kernel, g1, dim3(256), 0, stream,
                       input, w_ih_bf, b_ih, out);

    // Persistent cooperative recurrence: 64 WGs x 512 threads, 512 grid syncs.
    void* args[] = {(void*)&w_hh_bf, (void*)&h_bf, (void*)&b_hh,
                    (void*)&internal, (void*)&out};
    hipLaunchCooperativeKernel((void*)rnn_persistent, dim3(64), dim3(512),
                               args, 0, stream);
}

// Round 5
// 9777.589 us; speedup vs baseline: 1.3067x; 1.3067x over previous
//
#include <hip/hip_runtime.h>
#include <hip/hip_bf16.h>
#include <math.h>

#define Bb 64
#define Tt 512
#define Ii 1024
#define Hh 2048
#define NBLK 64

typedef __attribute__((ext_vector_type(8))) short bf16x8;
typedef __attribute__((ext_vector_type(8))) unsigned short ushort8;
typedef __attribute__((ext_vector_type(4))) float f32x4;

__device__ __forceinline__ unsigned short f2bf(float x) {
    unsigned int u = __float_as_uint(x);
    unsigned int r = u + 0x7fffu + ((u >> 16) & 1u);
    return (unsigned short)(r >> 16);
}

// Device-scope (agent) relaxed load of a 16B bf16 fragment: bypasses the
// non-coherent per-XCD L2s (sc1), reads from the coherence point (L3).
__device__ __forceinline__ bf16x8 load_frag_agent(const unsigned short* p) {
    union { bf16x8 v; unsigned long long q[2]; } u;
    const unsigned long long* q = (const unsigned long long*)p;
    u.q[0] = __hip_atomic_load(q + 0, __ATOMIC_RELAXED, __HIP_MEMORY_SCOPE_AGENT);
    u.q[1] = __hip_atomic_load(q + 1, __ATOMIC_RELAXED, __HIP_MEMORY_SCOPE_AGENT);
    return u.v;
}

// ---------------------------------------------------------------------------
__global__ __launch_bounds__(256) void cvt_kernel(
    const float* __restrict__ src, unsigned short* __restrict__ dst)
{
    const int i = (blockIdx.x * 256 + threadIdx.x) * 4;
    float4 v = *(const float4*)(src + i);
    ushort4 o;
    o.x = f2bf(v.x); o.y = f2bf(v.y); o.z = f2bf(v.z); o.w = f2bf(v.w);
    *(ushort4*)(dst + i) = o;
}

__global__ void init_cnt(unsigned int* cnt) { *cnt = 0u; }

// ---------------------------------------------------------------------------
// xproj: out[M=B*T][N=H] = input[M][K=I] @ w_ih^T + b_ih   (bf16 MFMA)
// (unchanged from round 3 — measured fine)
// ---------------------------------------------------------------------------
__global__ __launch_bounds__(256, 2) void xproj_kernel(
    const float* __restrict__ A,
    const unsigned short* __restrict__ Wbf,
    const float* __restrict__ bias,
    float* __restrict__ out)
{
    __shared__ unsigned short As[128 * 40];
    __shared__ unsigned short Bs[128 * 40];

    const int tid  = threadIdx.x;
    const int lane = tid & 63;
    const int wid  = tid >> 6;
    const int wm   = wid & 1;
    const int wn   = wid >> 1;
    const int rlo  = lane & 15;
    const int khi  = lane >> 4;

    const int m0 = blockIdx.y * 128;
    const int n0 = blockIdx.x * 128;

    f32x4 acc[4][4];
    #pragma unroll
    for (int i = 0; i < 4; ++i)
        #pragma unroll
        for (int j = 0; j < 4; ++j) acc[i][j] = (f32x4)0.f;

    for (int k0 = 0; k0 < Ii; k0 += 32) {
        #pragma unroll
        for (int p = 0; p < 4; ++p) {
            const int flat = p * 256 + tid;
            const int row  = flat >> 3;
            const int c4   = flat & 7;
            float4 v = *(const float4*)(A + (size_t)(m0 + row) * Ii + k0 + c4 * 4);
            ushort4 o;
            o.x = f2bf(v.x); o.y = f2bf(v.y); o.z = f2bf(v.z); o.w = f2bf(v.w);
            *(ushort4*)(As + row * 40 + c4 * 4) = o;
        }
        #pragma unroll
        for (int p = 0; p < 2; ++p) {
            const int flat = p * 256 + tid;
            const int row  = flat >> 2;
            const int c8   = flat & 3;
            ushort8 v = *(const ushort8*)(Wbf + (size_t)(n0 + row) * Ii + k0 + c8 * 8);
            *(ushort8*)(Bs + row * 40 + c8 * 8) = v;
        }
        __syncthreads();

        bf16x8 af[4], bfr[4];
        #pragma unroll
        for (int i = 0; i < 4; ++i)
            af[i] = *(const bf16x8*)(As + (wm * 64 + i * 16 + rlo) * 40 + khi * 8);
        #pragma unroll
        for (int j = 0; j < 4; ++j)
            bfr[j] = *(const bf16x8*)(Bs + (wn * 64 + j * 16 + rlo) * 40 + khi * 8);
        #pragma unroll
        for (int i = 0; i < 4; ++i)
            #pragma unroll
            for (int j = 0; j < 4; ++j)
                acc[i][j] = __builtin_amdgcn_mfma_f32_16x16x32_bf16(
                    af[i], bfr[j], acc[i][j], 0, 0, 0);
        __syncthreads();
    }

    #pragma unroll
    for (int j = 0; j < 4; ++j) {
        const int col = n0 + wn * 64 + j * 16 + rlo;
        const float bj = bias[col];
        #pragma unroll
        for (int i = 0; i < 4; ++i) {
            #pragma unroll
            for (int r = 0; r < 4; ++r) {
                const int m = m0 + wm * 64 + i * 16 + khi * 4 + r;
                out[(size_t)m * Hh + col] = acc[i][j][r] + bj;
            }
        }
    }
}

// ---------------------------------------------------------------------------
// Persistent recurrence: 64 WGs x 512 thr (8 waves). WG owns 32 cols.
// Wave wid = K-slice ks in 0..7 ([ks*256, +256)), covers BOTH 16-col tiles.
// w_hh slice (2 ntiles x 8 kit) held in 64 VGPRs for all 512 steps.
// h moves through device-scope relaxed atomics (sc1 -> L3); custom
// monotonic-counter barrier instead of cg::grid.sync (no L2 flush).
// ---------------------------------------------------------------------------
__global__ __launch_bounds__(512, 2) void rnn_persistent(
    const unsigned short* __restrict__ w_bf,   // [2048][2048] bf16
    unsigned short* __restrict__ h_bf,         // [2][64][2048] bf16 ping-pong
    const float* __restrict__ b_hh,            // [2048]
    const float* __restrict__ internal,        // [64][512]
    float* __restrict__ out,                   // [B][T][H] ++ [B][H]
    unsigned int* __restrict__ cnt)            // barrier counter (zeroed)
{
    __shared__ float red[8 * 2 * 4 * 64 * 4];  // [ks][nt][m][lane][er] = 64 KiB

    const int tid  = threadIdx.x;
    const int lane = tid & 63;
    const int wid  = tid >> 6;           // ks: K-slice 0..7
    const int rlo  = lane & 15;
    const int khi  = lane >> 4;
    const int blk  = blockIdx.x;         // 0..63 -> cols blk*32..+31

    // ---- preload w_hh slice into registers (lives for all 512 steps)
    bf16x8 wf[2][8];
    #pragma unroll
    for (int nt = 0; nt < 2; ++nt) {
        const unsigned short* wrow =
            w_bf + (size_t)(blk * 32 + nt * 16 + rlo) * Hh + wid * 256 + khi * 8;
        #pragma unroll
        for (int kit = 0; kit < 8; ++kit)
            wf[nt][kit] = *(const bf16x8*)(wrow + kit * 32);
    }

    // ---- epilogue ownership: thread -> col pair (gc0, gc0+1) x rows {rr, rr+32}
    const int cp  = tid & 15;
    const int rr  = tid >> 4;            // 0..31
    const int gc0 = blk * 32 + cp * 2;
    const float2 bh2 = *(const float2*)(b_hh + gc0);

    for (int t = 0; t < Tt; ++t) {
        const unsigned short* h_cur = h_bf + (size_t)(t & 1) * Bb * Hh;
        unsigned short*       h_nxt = h_bf + (size_t)((t + 1) & 1) * Bb * Hh;

        // prefetch epilogue operands (independent of h; hides under GEMM)
        float xp[2][2], nz[2];
        #pragma unroll
        for (int e = 0; e < 2; ++e) {
            const int row = rr + 32 * e;
            nz[e] = internal[row * Tt + t];
            float2 x2 = *(const float2*)(out + ((size_t)row * Tt + t) * Hh + gc0);
            xp[e][0] = x2.x; xp[e][1] = x2.y;
        }

        // ---- GEMM: this wave's 256-K slice, 64 rows x 32 cols
        const unsigned short* abase = h_cur + (size_t)rlo * Hh + wid * 256 + khi * 8;
        f32x4 acc[4][2];
        #pragma unroll
        for (int m = 0; m < 4; ++m)
            #pragma unroll
            for (int nt = 0; nt < 2; ++nt) acc[m][nt] = (f32x4)0.f;

        bf16x8 a0[4][2], a1[4][2];
        #pragma unroll
        for (int m = 0; m < 4; ++m)
            #pragma unroll
            for (int k2 = 0; k2 < 2; ++k2)
                a0[m][k2] = load_frag_agent(abase + (size_t)(m * 16) * Hh + k2 * 32);

        #pragma unroll
        for (int g = 0; g < 4; ++g) {
            if (g < 3) {   // prefetch next 2-kit group
                #pragma unroll
                for (int m = 0; m < 4; ++m)
                    #pragma unroll
                    for (int k2 = 0; k2 < 2; ++k2) {
                        bf16x8 v = load_frag_agent(
                            abase + (size_t)(m * 16) * Hh + ((g + 1) * 2 + k2) * 32);
                        if (g & 1) a0[m][k2] = v; else a1[m][k2] = v;
                    }
            }
            #pragma unroll
            for (int k2 = 0; k2 < 2; ++k2)
                #pragma unroll
                for (int m = 0; m < 4; ++m)
                    #pragma unroll
                    for (int nt = 0; nt < 2; ++nt) {
                        bf16x8 av = (g & 1) ? a1[m][k2] : a0[m][k2];
                        acc[m][nt] = __builtin_amdgcn_mfma_f32_16x16x32_bf16(
                            av, wf[nt][g * 2 + k2], acc[m][nt], 0, 0, 0);
                    }
        }

        // ---- 8-way k-split reduce through LDS
        #pragma unroll
        for (int nt = 0; nt < 2; ++nt)
            #pragma unroll
            for (int m = 0; m < 4; ++m)
                *(f32x4*)(red + (((wid * 2 + nt) * 4 + m) * 64 + lane) * 4) = acc[m][nt];
        __syncthreads();

        // ---- epilogue: 2 rows x 2 cols per thread
        #pragma unroll
        for (int e = 0; e < 2; ++e) {
            const int row = rr + 32 * e;
            const int m   = row >> 4;
            const int rl  = row & 15;
            const int er  = rl & 3;
            float g01[2];
            #pragma unroll
            for (int j = 0; j < 2; ++j) {
                const int c  = cp * 2 + j;
                const int nt = c >> 4;
                const int cl = c & 15;
                const int li = (rl >> 2) * 16 + cl;
                float s = 0.f;
                #pragma unroll
                for (int ks = 0; ks < 8; ++ks)
                    s += red[(((ks * 2 + nt) * 4 + m) * 64 + li) * 4 + er];
                g01[j] = tanhf(xp[e][j] + nz[e] + (j == 0 ? bh2.x : bh2.y) + s);
            }
            float2 o2 = {g01[0], g01[1]};
            *(float2*)(out + ((size_t)row * Tt + t) * Hh + gc0) = o2;
            const unsigned int hp =
                (unsigned int)f2bf(g01[0]) | ((unsigned int)f2bf(g01[1]) << 16);
            __hip_atomic_store((unsigned int*)h_nxt + ((size_t)row * Hh + gc0) / 2,
                               hp, __ATOMIC_RELAXED, __HIP_MEMORY_SCOPE_AGENT);
            if (t == Tt - 1)
                *(float2*)(out + (size_t)Bb * Tt * Hh + (size_t)row * Hh + gc0) = o2;
        }

        // ---- cheap grid barrier (skip after last step)
        if (t < Tt - 1) {
            asm volatile("s_waitcnt vmcnt(0)" ::: "memory");  // h stores at L3
            __syncthreads();                                  // whole block done
            if (tid == 0) {
                __hip_atomic_fetch_add(cnt, 1u, __ATOMIC_RELAXED,
                                       __HIP_MEMORY_SCOPE_AGENT);
                const unsigned int target = (unsigned int)NBLK * (unsigned int)(t + 1);
                while (__hip_atomic_load(cnt, __ATOMIC_RELAXED,
                                         __HIP_MEMORY_SCOPE_AGENT) < target)
                    __builtin_amdgcn_s_sleep(2);
            }
            __syncthreads();
        }
    }
}

// ---------------------------------------------------------------------------
extern "C" void kernel_launch(void* const* d_in, const int* in_sizes, int n_in,
                              void* d_out, int out_size, void* d_ws, size_t ws_size,
                              hipStream_t stream) {
    const float* input    = (const float*)d_in[0];
    const float* internal = (const float*)d_in[1];
    const float* w_ih     = (const float*)d_in[2];
    const float* w_hh     = (const float*)d_in[3];
    const float* b_ih     = (const float*)d_in[4];
    const float* b_hh     = (const float*)d_in[5];
    const float* h0       = (const float*)d_in[6];
    float* out = (float*)d_out;

    // ws: w_hh_bf [4M us] | w_ih_bf [2M us] | h_bf[2][64][2048] | cnt
    unsigned short* w_hh_bf = (unsigned short*)d_ws;
    unsigned short* w_ih_bf = w_hh_bf + (size_t)Hh * Hh;
    unsigned short* h_bf    = w_ih_bf + (size_t)Hh * Ii;
    unsigned int*   cnt     = (unsigned int*)(h_bf + (size_t)2 * Bb * Hh);

    hipLaunchKernelGGL(init_cnt, dim3(1), dim3(1), 0, stream, cnt);
    hipLaunchKernelGGL(cvt_kernel, dim3((Hh * Hh) / 1024), dim3(256), 0, stream,
                       w_hh, w_hh_bf);
    hipLaunchKernelGGL(cvt_kernel, dim3((Hh * Ii) / 1024), dim3(256), 0, stream,
                       w_ih, w_ih_bf);
    hipLaunchKernelGGL(cvt_kernel, dim3((Bb * Hh) / 1024), dim3(256), 0, stream,
                       h0, h_bf);

    dim3 g1(Hh / 128, (Bb * Tt) / 128);
    hipLaunchKernelGGL(xproj_kernel, g1, dim3(256), 0, stream,
                       input, w_ih_bf, b_ih, out);

    void* args[] = {(void*)&w_hh_bf, (void*)&h_bf, (void*)&b_hh,
                    (void*)&internal, (void*)&out, (void*)&cnt};
    hipLaunchCooperativeKernel((void*)rnn_persistent, dim3(NBLK), dim3(512),
                               args, 0, stream);
}

// Round 6
// 8764.948 us; speedup vs baseline: 1.4576x; 1.1155x over previous
//
#include <hip/hip_runtime.h>
#include <hip/hip_bf16.h>
#include <math.h>

#define Bb 64
#define Tt 512
#define Ii 1024
#define Hh 2048
#define NBLK 64

typedef __attribute__((ext_vector_type(8))) short bf16x8;
typedef __attribute__((ext_vector_type(8))) unsigned short ushort8;
typedef __attribute__((ext_vector_type(4))) float f32x4;

__device__ __forceinline__ unsigned short f2bf(float x) {
    unsigned int u = __float_as_uint(x);
    unsigned int r = u + 0x7fffu + ((u >> 16) & 1u);
    return (unsigned short)(r >> 16);
}

// Device-scope (agent) relaxed load: bypasses non-coherent per-XCD L2s.
__device__ __forceinline__ bf16x8 load_frag_agent(const unsigned short* p) {
    union { bf16x8 v; unsigned long long q[2]; } u;
    const unsigned long long* q = (const unsigned long long*)p;
    u.q[0] = __hip_atomic_load(q + 0, __ATOMIC_RELAXED, __HIP_MEMORY_SCOPE_AGENT);
    u.q[1] = __hip_atomic_load(q + 1, __ATOMIC_RELAXED, __HIP_MEMORY_SCOPE_AGENT);
    return u.v;
}

// ---------------------------------------------------------------------------
__global__ __launch_bounds__(256) void cvt_kernel(
    const float* __restrict__ src, unsigned short* __restrict__ dst)
{
    const int i = (blockIdx.x * 256 + threadIdx.x) * 4;
    float4 v = *(const float4*)(src + i);
    ushort4 o;
    o.x = f2bf(v.x); o.y = f2bf(v.y); o.z = f2bf(v.z); o.w = f2bf(v.w);
    *(ushort4*)(dst + i) = o;
}

__global__ void init_flags(unsigned int* flags) { flags[threadIdx.x] = 0u; }

// ---------------------------------------------------------------------------
// xproj: out[M=B*T][N=H] = input[M][K=I] @ w_ih^T + b_ih   (bf16 MFMA)
// ---------------------------------------------------------------------------
__global__ __launch_bounds__(256, 2) void xproj_kernel(
    const float* __restrict__ A,
    const unsigned short* __restrict__ Wbf,
    const float* __restrict__ bias,
    float* __restrict__ out)
{
    __shared__ unsigned short As[128 * 40];
    __shared__ unsigned short Bs[128 * 40];

    const int tid  = threadIdx.x;
    const int lane = tid & 63;
    const int wid  = tid >> 6;
    const int wm   = wid & 1;
    const int wn   = wid >> 1;
    const int rlo  = lane & 15;
    const int khi  = lane >> 4;

    const int m0 = blockIdx.y * 128;
    const int n0 = blockIdx.x * 128;

    f32x4 acc[4][4];
    #pragma unroll
    for (int i = 0; i < 4; ++i)
        #pragma unroll
        for (int j = 0; j < 4; ++j) acc[i][j] = (f32x4)0.f;

    for (int k0 = 0; k0 < Ii; k0 += 32) {
        #pragma unroll
        for (int p = 0; p < 4; ++p) {
            const int flat = p * 256 + tid;
            const int row  = flat >> 3;
            const int c4   = flat & 7;
            float4 v = *(const float4*)(A + (size_t)(m0 + row) * Ii + k0 + c4 * 4);
            ushort4 o;
            o.x = f2bf(v.x); o.y = f2bf(v.y); o.z = f2bf(v.z); o.w = f2bf(v.w);
            *(ushort4*)(As + row * 40 + c4 * 4) = o;
        }
        #pragma unroll
        for (int p = 0; p < 2; ++p) {
            const int flat = p * 256 + tid;
            const int row  = flat >> 2;
            const int c8   = flat & 3;
            ushort8 v = *(const ushort8*)(Wbf + (size_t)(n0 + row) * Ii + k0 + c8 * 8);
            *(ushort8*)(Bs + row * 40 + c8 * 8) = v;
        }
        __syncthreads();

        bf16x8 af[4], bfr[4];
        #pragma unroll
        for (int i = 0; i < 4; ++i)
            af[i] = *(const bf16x8*)(As + (wm * 64 + i * 16 + rlo) * 40 + khi * 8);
        #pragma unroll
        for (int j = 0; j < 4; ++j)
            bfr[j] = *(const bf16x8*)(Bs + (wn * 64 + j * 16 + rlo) * 40 + khi * 8);
        #pragma unroll
        for (int i = 0; i < 4; ++i)
            #pragma unroll
            for (int j = 0; j < 4; ++j)
                acc[i][j] = __builtin_amdgcn_mfma_f32_16x16x32_bf16(
                    af[i], bfr[j], acc[i][j], 0, 0, 0);
        __syncthreads();
    }

    #pragma unroll
    for (int j = 0; j < 4; ++j) {
        const int col = n0 + wn * 64 + j * 16 + rlo;
        const float bj = bias[col];
        #pragma unroll
        for (int i = 0; i < 4; ++i) {
            #pragma unroll
            for (int r = 0; r < 4; ++r) {
                const int m = m0 + wm * 64 + i * 16 + khi * 4 + r;
                out[(size_t)m * Hh + col] = acc[i][j][r] + bj;
            }
        }
    }
}

// ---------------------------------------------------------------------------
// Persistent recurrence: 64 WGs x 512 thr (8 waves). WG owns 32 cols.
// Wave wid = K-slice [wid*256, +256). w_hh slice register-resident.
// Barrier: per-WG flag store (no RMW contention) + 64-lane coalesced poll.
// Reduce: f32x4 LDS stripes, writer idx == reader idx == tid (conflict-free).
// ---------------------------------------------------------------------------
__global__ __launch_bounds__(512, 1) void rnn_persistent(
    const unsigned short* __restrict__ w_bf,   // [2048][2048] bf16
    unsigned short* __restrict__ h_bf,         // [2][64][2048] bf16 ping-pong
    const float* __restrict__ b_hh,            // [2048]
    const float* __restrict__ internal,        // [64][512]
    float* __restrict__ out,                   // [B][T][H] ++ [B][H]
    unsigned int* __restrict__ flags)          // [NBLK] arrival flags (zeroed)
{
    __shared__ f32x4 red4[8 * 512];            // 64 KiB

    const int tid  = threadIdx.x;
    const int lane = tid & 63;
    const int wid  = tid >> 6;                 // K-slice 0..7
    const int rlo  = lane & 15;
    const int khi  = lane >> 4;
    const int blk  = blockIdx.x;               // cols blk*32..+31

    // ---- preload w_hh slice into registers (lives for all 512 steps)
    bf16x8 wf[2][8];
    #pragma unroll
    for (int nt = 0; nt < 2; ++nt) {
        const unsigned short* wrow =
            w_bf + (size_t)(blk * 32 + nt * 16 + rlo) * Hh + wid * 256 + khi * 8;
        #pragma unroll
        for (int kit = 0; kit < 8; ++kit)
            wf[nt][kit] = *(const bf16x8*)(wrow + kit * 32);
    }

    // ---- epilogue decode: thread tid owns cell (m=wid&3, nt=wid>>2, lane)
    //      col = nt*16 + (lane&15), rows = m*16 + (lane>>4)*4 + er
    //      shfl_xor(1) pairs adjacent cols: even lane -> rows er=0,1 of col pair,
    //      odd lane -> rows er=2,3 of col pair.
    const int em    = wid & 3;
    const int ent   = wid >> 2;
    const int ecol  = blk * 32 + ent * 16 + rlo;
    const int odd   = lane & 1;
    const int cl    = ecol & ~1;               // even col of the pair
    const int erow0 = em * 16 + khi * 4;
    const int rA    = erow0 + 2 * odd;
    const int rB    = rA + 1;
    const float2 bh2 = *(const float2*)(b_hh + cl);

    // prologue prefetch for t = 0
    float2 xpA = *(const float2*)(out + ((size_t)rA * Tt + 0) * Hh + cl);
    float2 xpB = *(const float2*)(out + ((size_t)rB * Tt + 0) * Hh + cl);
    float  nzA = internal[rA * Tt + 0];
    float  nzB = internal[rB * Tt + 0];

    for (int t = 0; t < Tt; ++t) {
        const unsigned short* h_cur = h_bf + (size_t)(t & 1) * Bb * Hh;
        unsigned short*       h_nxt = h_bf + (size_t)((t + 1) & 1) * Bb * Hh;

        // ---- GEMM: this wave's 256-K slice, 64 rows x 32 cols
        const unsigned short* abase = h_cur + (size_t)rlo * Hh + wid * 256 + khi * 8;
        f32x4 acc[4][2];
        #pragma unroll
        for (int m = 0; m < 4; ++m)
            #pragma unroll
            for (int nt = 0; nt < 2; ++nt) acc[m][nt] = (f32x4)0.f;

        bf16x8 a0[4][2], a1[4][2];
        #pragma unroll
        for (int m = 0; m < 4; ++m)
            #pragma unroll
            for (int k2 = 0; k2 < 2; ++k2)
                a0[m][k2] = load_frag_agent(abase + (size_t)(m * 16) * Hh + k2 * 32);

        #pragma unroll
        for (int g = 0; g < 4; ++g) {
            if (g < 3) {
                #pragma unroll
                for (int m = 0; m < 4; ++m)
                    #pragma unroll
                    for (int k2 = 0; k2 < 2; ++k2) {
                        bf16x8 v = load_frag_agent(
                            abase + (size_t)(m * 16) * Hh + ((g + 1) * 2 + k2) * 32);
                        if (g & 1) a0[m][k2] = v; else a1[m][k2] = v;
                    }
            }
            #pragma unroll
            for (int k2 = 0; k2 < 2; ++k2)
                #pragma unroll
                for (int m = 0; m < 4; ++m)
                    #pragma unroll
                    for (int nt = 0; nt < 2; ++nt) {
                        bf16x8 av = (g & 1) ? a1[m][k2] : a0[m][k2];
                        acc[m][nt] = __builtin_amdgcn_mfma_f32_16x16x32_bf16(
                            av, wf[nt][g * 2 + k2], acc[m][nt], 0, 0, 0);
                    }
        }

        // ---- 8-way k-split reduce: writer idx (nt*4+m)*64+lane ; reader idx tid
        #pragma unroll
        for (int nt = 0; nt < 2; ++nt)
            #pragma unroll
            for (int m = 0; m < 4; ++m)
                red4[wid * 512 + (nt * 4 + m) * 64 + lane] = acc[m][nt];
        __syncthreads();

        f32x4 s4 = (f32x4)0.f;
        #pragma unroll
        for (int ks = 0; ks < 8; ++ks)
            s4 += red4[ks * 512 + tid];

        // ---- pair adjacent cols via shfl_xor(1)
        f32x4 o4;
        #pragma unroll
        for (int i = 0; i < 4; ++i)
            o4[i] = __shfl_xor(s4[i], 1, 64);

        const float sA_lo = odd ? o4[2] : s4[0];
        const float sA_hi = odd ? s4[2] : o4[0];
        const float sB_lo = odd ? o4[3] : s4[1];
        const float sB_hi = odd ? s4[3] : o4[1];

        float2 gA, gB;
        gA.x = tanhf(xpA.x + nzA + bh2.x + sA_lo);
        gA.y = tanhf(xpA.y + nzA + bh2.y + sA_hi);
        gB.x = tanhf(xpB.x + nzB + bh2.x + sB_lo);
        gB.y = tanhf(xpB.y + nzB + bh2.y + sB_hi);

        // ---- h_nxt stores (agent scope, write-through to coherence point)
        const unsigned int hpA =
            (unsigned int)f2bf(gA.x) | ((unsigned int)f2bf(gA.y) << 16);
        const unsigned int hpB =
            (unsigned int)f2bf(gB.x) | ((unsigned int)f2bf(gB.y) << 16);
        __hip_atomic_store((unsigned int*)h_nxt + ((size_t)rA * Hh + cl) / 2,
                           hpA, __ATOMIC_RELAXED, __HIP_MEMORY_SCOPE_AGENT);
        __hip_atomic_store((unsigned int*)h_nxt + ((size_t)rB * Hh + cl) / 2,
                           hpB, __ATOMIC_RELAXED, __HIP_MEMORY_SCOPE_AGENT);

        const bool last = (t == Tt - 1);
        if (!last) {
            // arrive: h stores globally visible, then flag
            asm volatile("s_waitcnt vmcnt(0)" ::: "memory");
            __syncthreads();
            if (tid == 0)
                __hip_atomic_store(flags + blk, (unsigned int)(t + 1),
                                   __ATOMIC_RELAXED, __HIP_MEMORY_SCOPE_AGENT);
        }

        // ---- out stores + next-step prefetch overlap the arrival skew
        *(float2*)(out + ((size_t)rA * Tt + t) * Hh + cl) = gA;
        *(float2*)(out + ((size_t)rB * Tt + t) * Hh + cl) = gB;
        if (last) {
            float* tail = out + (size_t)Bb * Tt * Hh;
            *(float2*)(tail + (size_t)rA * Hh + cl) = gA;
            *(float2*)(tail + (size_t)rB * Hh + cl) = gB;
        } else {
            xpA = *(const float2*)(out + ((size_t)rA * Tt + t + 1) * Hh + cl);
            xpB = *(const float2*)(out + ((size_t)rB * Tt + t + 1) * Hh + cl);
            nzA = internal[rA * Tt + t + 1];
            nzB = internal[rB * Tt + t + 1];

            // wait: wave 0 polls all 64 flags with one coalesced agent load
            if (wid == 0) {
                const unsigned int tgt = (unsigned int)(t + 1);
                while (true) {
                    unsigned int f = __hip_atomic_load(
                        flags + lane, __ATOMIC_RELAXED, __HIP_MEMORY_SCOPE_AGENT);
                    if (__all(f >= tgt)) break;
                }
            }
            __syncthreads();
        }
    }
}

// ---------------------------------------------------------------------------
extern "C" void kernel_launch(void* const* d_in, const int* in_sizes, int n_in,
                              void* d_out, int out_size, void* d_ws, size_t ws_size,
                              hipStream_t stream) {
    const float* input    = (const float*)d_in[0];
    const float* internal = (const float*)d_in[1];
    const float* w_ih     = (const float*)d_in[2];
    const float* w_hh     = (const float*)d_in[3];
    const float* b_ih     = (const float*)d_in[4];
    const float* b_hh     = (const float*)d_in[5];
    const float* h0       = (const float*)d_in[6];
    float* out = (float*)d_out;

    // ws: w_hh_bf [4M us] | w_ih_bf [2M us] | h_bf[2][64][2048] | flags[64]
    unsigned short* w_hh_bf = (unsigned short*)d_ws;
    unsigned short* w_ih_bf = w_hh_bf + (size_t)Hh * Hh;
    unsigned short* h_bf    = w_ih_bf + (size_t)Hh * Ii;
    unsigned int*   flags   = (unsigned int*)(h_bf + (size_t)2 * Bb * Hh);

    hipLaunchKernelGGL(init_flags, dim3(1), dim3(NBLK), 0, stream, flags);
    hipLaunchKernelGGL(cvt_kernel, dim3((Hh * Hh) / 1024), dim3(256), 0, stream,
                       w_hh, w_hh_bf);
    hipLaunchKernelGGL(cvt_kernel, dim3((Hh * Ii) / 1024), dim3(256), 0, stream,
                       w_ih, w_ih_bf);
    hipLaunchKernelGGL(cvt_kernel, dim3((Bb * Hh) / 1024), dim3(256), 0, stream,
                       h0, h_bf);

    dim3 g1(Hh / 128, (Bb * Tt) / 128);
    hipLaunchKernelGGL(xproj_kernel, g1, dim3(256), 0, stream,
                       input, w_ih_bf, b_ih, out);

    void* args[] = {(void*)&w_hh_bf, (void*)&h_bf, (void*)&b_hh,
                    (void*)&internal, (void*)&out, (void*)&flags};
    hipLaunchCooperativeKernel((void*)rnn_persistent, dim3(NBLK), dim3(512),
                               args, 0, stream);
}

// Round 8
// 5418.871 us; speedup vs baseline: 2.3577x; 1.6175x over previous
//
#include <hip/hip_runtime.h>
#include <hip/hip_bf16.h>
#include <math.h>

#define Bb 64
#define Tt 512
#define Ii 1024
#define Hh 2048
#define NBLK 64

typedef __attribute__((ext_vector_type(8))) short bf16x8;
typedef __attribute__((ext_vector_type(8))) unsigned short ushort8;
typedef __attribute__((ext_vector_type(4))) float f32x4;

__device__ __forceinline__ unsigned short f2bf(float x) {
    unsigned int u = __float_as_uint(x);
    unsigned int r = u + 0x7fffu + ((u >> 16) & 1u);
    return (unsigned short)(r >> 16);
}

// ---------------------------------------------------------------------------
__global__ __launch_bounds__(256) void cvt_kernel(
    const float* __restrict__ src, unsigned short* __restrict__ dst)
{
    const int i = (blockIdx.x * 256 + threadIdx.x) * 4;
    float4 v = *(const float4*)(src + i);
    ushort4 o;
    o.x = f2bf(v.x); o.y = f2bf(v.y); o.z = f2bf(v.z); o.w = f2bf(v.w);
    *(ushort4*)(dst + i) = o;
}

__global__ void init_flags(unsigned int* flags) { flags[threadIdx.x] = 0u; }

// ---------------------------------------------------------------------------
// xproj: out[M=B*T][N=H] = input[M][K=I] @ w_ih^T + b_ih   (bf16 MFMA)
// ---------------------------------------------------------------------------
__global__ __launch_bounds__(256, 2) void xproj_kernel(
    const float* __restrict__ A,
    const unsigned short* __restrict__ Wbf,
    const float* __restrict__ bias,
    float* __restrict__ out)
{
    __shared__ unsigned short As[128 * 40];
    __shared__ unsigned short Bs[128 * 40];

    const int tid  = threadIdx.x;
    const int lane = tid & 63;
    const int wid  = tid >> 6;
    const int wm   = wid & 1;
    const int wn   = wid >> 1;
    const int rlo  = lane & 15;
    const int khi  = lane >> 4;

    const int m0 = blockIdx.y * 128;
    const int n0 = blockIdx.x * 128;

    f32x4 acc[4][4];
    #pragma unroll
    for (int i = 0; i < 4; ++i)
        #pragma unroll
        for (int j = 0; j < 4; ++j) acc[i][j] = (f32x4)0.f;

    for (int k0 = 0; k0 < Ii; k0 += 32) {
        #pragma unroll
        for (int p = 0; p < 4; ++p) {
            const int flat = p * 256 + tid;
            const int row  = flat >> 3;
            const int c4   = flat & 7;
            float4 v = *(const float4*)(A + (size_t)(m0 + row) * Ii + k0 + c4 * 4);
            ushort4 o;
            o.x = f2bf(v.x); o.y = f2bf(v.y); o.z = f2bf(v.z); o.w = f2bf(v.w);
            *(ushort4*)(As + row * 40 + c4 * 4) = o;
        }
        #pragma unroll
        for (int p = 0; p < 2; ++p) {
            const int flat = p * 256 + tid;
            const int row  = flat >> 2;
            const int c8   = flat & 3;
            ushort8 v = *(const ushort8*)(Wbf + (size_t)(n0 + row) * Ii + k0 + c8 * 8);
            *(ushort8*)(Bs + row * 40 + c8 * 8) = v;
        }
        __syncthreads();

        bf16x8 af[4], bfr[4];
        #pragma unroll
        for (int i = 0; i < 4; ++i)
            af[i] = *(const bf16x8*)(As + (wm * 64 + i * 16 + rlo) * 40 + khi * 8);
        #pragma unroll
        for (int j = 0; j < 4; ++j)
            bfr[j] = *(const bf16x8*)(Bs + (wn * 64 + j * 16 + rlo) * 40 + khi * 8);
        #pragma unroll
        for (int i = 0; i < 4; ++i)
            #pragma unroll
            for (int j = 0; j < 4; ++j)
                acc[i][j] = __builtin_amdgcn_mfma_f32_16x16x32_bf16(
                    af[i], bfr[j], acc[i][j], 0, 0, 0);
        __syncthreads();
    }

    #pragma unroll
    for (int j = 0; j < 4; ++j) {
        const int col = n0 + wn * 64 + j * 16 + rlo;
        const float bj = bias[col];
        #pragma unroll
        for (int i = 0; i < 4; ++i) {
            #pragma unroll
            for (int r = 0; r < 4; ++r) {
                const int m = m0 + wm * 64 + i * 16 + khi * 4 + r;
                out[(size_t)m * Hh + col] = acc[i][j][r] + bj;
            }
        }
    }
}

// ---------------------------------------------------------------------------
// asm helpers: system-scope (L2-bypassing) 16B load; drain-based waits only
// (vmcnt(0) is robust against any compiler-inserted VMEM ops / spills).
// ---------------------------------------------------------------------------
#define LD_FRAG(dst, base, OFF)                                               \
    asm volatile("global_load_dwordx4 %0, %1, off offset:" OFF " sc0 sc1"     \
                 : "=v"(dst) : "v"(base))

// Full drain tying all 16 fragments of a batch: consumers are data-ordered
// after the wait; sched_barrier stops MFMA hoisting (rule 18).
#define DRAIN16(a)                                                            \
    asm volatile("s_waitcnt vmcnt(0)"                                         \
                 : "+v"(a[0][0]), "+v"(a[0][1]), "+v"(a[0][2]), "+v"(a[0][3]),\
                   "+v"(a[1][0]), "+v"(a[1][1]), "+v"(a[1][2]), "+v"(a[1][3]),\
                   "+v"(a[2][0]), "+v"(a[2][1]), "+v"(a[2][2]), "+v"(a[2][3]),\
                   "+v"(a[3][0]), "+v"(a[3][1]), "+v"(a[3][2]), "+v"(a[3][3]) \
                 :: "memory");                                                \
    __builtin_amdgcn_sched_barrier(0)

template <int KB>
__device__ __forceinline__ void mfma_batch4(const bf16x8 (&a)[4][4],
                                            const bf16x8 (&wf)[2][8],
                                            f32x4 (&acc)[4][2]) {
#pragma unroll
    for (int kk = 0; kk < 4; ++kk)
#pragma unroll
        for (int m = 0; m < 4; ++m)
#pragma unroll
            for (int nt = 0; nt < 2; ++nt)
                acc[m][nt] = __builtin_amdgcn_mfma_f32_16x16x32_bf16(
                    a[m][kk], wf[nt][KB + kk], acc[m][nt], 0, 0, 0);
}

// ---------------------------------------------------------------------------
// Persistent recurrence: 64 WGs x 512 thr (8 waves). WG owns 32 cols.
// Wave wid = K-slice [wid*256, +256). w_hh slice register-resident.
// h loads: 16-wide pipelined asm sc0sc1 batches, vmcnt(0) drains only.
// Everything else identical to the round-6 kernel (verified PASS).
// ---------------------------------------------------------------------------
__global__ __launch_bounds__(512, 1) void rnn_persistent(
    const unsigned short* __restrict__ w_bf,   // [2048][2048] bf16
    unsigned short* __restrict__ h_bf,         // [2][64][2048] bf16 ping-pong
    const float* __restrict__ b_hh,            // [2048]
    const float* __restrict__ internal,        // [64][512]
    float* __restrict__ out,                   // [B][T][H] ++ [B][H]
    unsigned int* __restrict__ flags)          // [NBLK] arrival flags (zeroed)
{
    __shared__ f32x4 red4[8 * 512];            // 64 KiB

    const int tid  = threadIdx.x;
    const int lane = tid & 63;
    const int wid  = tid >> 6;                 // K-slice 0..7
    const int rlo  = lane & 15;
    const int khi  = lane >> 4;
    const int blk  = blockIdx.x;               // cols blk*32..+31

    // ---- preload w_hh slice into registers (lives for all 512 steps)
    bf16x8 wf[2][8];
    #pragma unroll
    for (int nt = 0; nt < 2; ++nt) {
        const unsigned short* wrow =
            w_bf + (size_t)(blk * 32 + nt * 16 + rlo) * Hh + wid * 256 + khi * 8;
        #pragma unroll
        for (int kit = 0; kit < 8; ++kit)
            wf[nt][kit] = *(const bf16x8*)(wrow + kit * 32);
    }

    // ---- epilogue decode (round-6 verified)
    const int ent   = wid >> 2;
    const int ecol  = blk * 32 + ent * 16 + rlo;
    const int odd   = lane & 1;
    const int cl    = ecol & ~1;               // even col of the pair
    const int em    = wid & 3;
    const int erow0 = em * 16 + khi * 4;
    const int rA    = erow0 + 2 * odd;
    const int rB    = rA + 1;
    const float2 bh2 = *(const float2*)(b_hh + cl);

    // prologue prefetch for t = 0
    float2 xpA = *(const float2*)(out + ((size_t)rA * Tt + 0) * Hh + cl);
    float2 xpB = *(const float2*)(out + ((size_t)rB * Tt + 0) * Hh + cl);
    float  nzA = internal[rA * Tt + 0];
    float  nzB = internal[rB * Tt + 0];

    for (int t = 0; t < Tt; ++t) {
        const unsigned short* h_cur = h_bf + (size_t)(t & 1) * Bb * Hh;
        unsigned short*       h_nxt = h_bf + (size_t)((t + 1) & 1) * Bb * Hh;

        // ---- GEMM: this wave's 256-K slice, 64 rows x 32 cols.
        // Two 16-fragment batches; within a batch all loads pipeline and a
        // single vmcnt(0) drain releases them together.
        const unsigned short* am0 = h_cur + (size_t)rlo * Hh + wid * 256 + khi * 8;
        const unsigned short* am1 = am0 + (size_t)16 * Hh;
        const unsigned short* am2 = am0 + (size_t)32 * Hh;
        const unsigned short* am3 = am0 + (size_t)48 * Hh;

        f32x4 acc[4][2];
        #pragma unroll
        for (int m = 0; m < 4; ++m)
            #pragma unroll
            for (int nt = 0; nt < 2; ++nt) acc[m][nt] = (f32x4)0.f;

        bf16x8 a[4][4];
        // batch 1: kits 0..3 (byte offsets 0,64,128,192)
        LD_FRAG(a[0][0], am0, "0");  LD_FRAG(a[0][1], am0, "64");
        LD_FRAG(a[0][2], am0, "128"); LD_FRAG(a[0][3], am0, "192");
        LD_FRAG(a[1][0], am1, "0");  LD_FRAG(a[1][1], am1, "64");
        LD_FRAG(a[1][2], am1, "128"); LD_FRAG(a[1][3], am1, "192");
        LD_FRAG(a[2][0], am2, "0");  LD_FRAG(a[2][1], am2, "64");
        LD_FRAG(a[2][2], am2, "128"); LD_FRAG(a[2][3], am2, "192");
        LD_FRAG(a[3][0], am3, "0");  LD_FRAG(a[3][1], am3, "64");
        LD_FRAG(a[3][2], am3, "128"); LD_FRAG(a[3][3], am3, "192");
        DRAIN16(a);
        mfma_batch4<0>(a, wf, acc);

        // batch 2: kits 4..7 (byte offsets 256,320,384,448), reuse regs
        LD_FRAG(a[0][0], am0, "256"); LD_FRAG(a[0][1], am0, "320");
        LD_FRAG(a[0][2], am0, "384"); LD_FRAG(a[0][3], am0, "448");
        LD_FRAG(a[1][0], am1, "256"); LD_FRAG(a[1][1], am1, "320");
        LD_FRAG(a[1][2], am1, "384"); LD_FRAG(a[1][3], am1, "448");
        LD_FRAG(a[2][0], am2, "256"); LD_FRAG(a[2][1], am2, "320");
        LD_FRAG(a[2][2], am2, "384"); LD_FRAG(a[2][3], am2, "448");
        LD_FRAG(a[3][0], am3, "256"); LD_FRAG(a[3][1], am3, "320");
        LD_FRAG(a[3][2], am3, "384"); LD_FRAG(a[3][3], am3, "448");
        DRAIN16(a);
        mfma_batch4<4>(a, wf, acc);

        // ---- 8-way k-split reduce: writer idx (nt*4+m)*64+lane ; reader tid
        #pragma unroll
        for (int nt = 0; nt < 2; ++nt)
            #pragma unroll
            for (int m = 0; m < 4; ++m)
                red4[wid * 512 + (nt * 4 + m) * 64 + lane] = acc[m][nt];
        __syncthreads();

        f32x4 s4 = (f32x4)0.f;
        #pragma unroll
        for (int ks = 0; ks < 8; ++ks)
            s4 += red4[ks * 512 + tid];

        // ---- pair adjacent cols via shfl_xor(1)
        f32x4 o4;
        #pragma unroll
        for (int i = 0; i < 4; ++i)
            o4[i] = __shfl_xor(s4[i], 1, 64);

        const float sA_lo = odd ? o4[2] : s4[0];
        const float sA_hi = odd ? s4[2] : o4[0];
        const float sB_lo = odd ? o4[3] : s4[1];
        const float sB_hi = odd ? s4[3] : o4[1];

        float2 gA, gB;
        gA.x = tanhf(xpA.x + nzA + bh2.x + sA_lo);
        gA.y = tanhf(xpA.y + nzA + bh2.y + sA_hi);
        gB.x = tanhf(xpB.x + nzB + bh2.x + sB_lo);
        gB.y = tanhf(xpB.y + nzB + bh2.y + sB_hi);

        // ---- h_nxt stores (agent scope, write-through to coherence point)
        const unsigned int hpA =
            (unsigned int)f2bf(gA.x) | ((unsigned int)f2bf(gA.y) << 16);
        const unsigned int hpB =
            (unsigned int)f2bf(gB.x) | ((unsigned int)f2bf(gB.y) << 16);
        __hip_atomic_store((unsigned int*)h_nxt + ((size_t)rA * Hh + cl) / 2,
                           hpA, __ATOMIC_RELAXED, __HIP_MEMORY_SCOPE_AGENT);
        __hip_atomic_store((unsigned int*)h_nxt + ((size_t)rB * Hh + cl) / 2,
                           hpB, __ATOMIC_RELAXED, __HIP_MEMORY_SCOPE_AGENT);

        const bool last = (t == Tt - 1);
        if (!last) {
            // arrive: h stores globally visible, then flag
            asm volatile("s_waitcnt vmcnt(0)" ::: "memory");
            __syncthreads();
            if (tid == 0)
                __hip_atomic_store(flags + blk, (unsigned int)(t + 1),
                                   __ATOMIC_RELAXED, __HIP_MEMORY_SCOPE_AGENT);
        }

        // ---- out stores + next-step prefetch overlap the arrival skew
        *(float2*)(out + ((size_t)rA * Tt + t) * Hh + cl) = gA;
        *(float2*)(out + ((size_t)rB * Tt + t) * Hh + cl) = gB;
        if (last) {
            float* tail = out + (size_t)Bb * Tt * Hh;
            *(float2*)(tail + (size_t)rA * Hh + cl) = gA;
            *(float2*)(tail + (size_t)rB * Hh + cl) = gB;
        } else {
            xpA = *(const float2*)(out + ((size_t)rA * Tt + t + 1) * Hh + cl);
            xpB = *(const float2*)(out + ((size_t)rB * Tt + t + 1) * Hh + cl);
            nzA = internal[rA * Tt + t + 1];
            nzB = internal[rB * Tt + t + 1];

            // wait: wave 0 polls all 64 flags with one coalesced agent load
            if (wid == 0) {
                const unsigned int tgt = (unsigned int)(t + 1);
                while (true) {
                    unsigned int f = __hip_atomic_load(
                        flags + lane, __ATOMIC_RELAXED, __HIP_MEMORY_SCOPE_AGENT);
                    if (__all(f >= tgt)) break;
                }
            }
            __syncthreads();
        }
    }
}

// ---------------------------------------------------------------------------
extern "C" void kernel_launch(void* const* d_in, const int* in_sizes, int n_in,
                              void* d_out, int out_size, void* d_ws, size_t ws_size,
                              hipStream_t stream) {
    const float* input    = (const float*)d_in[0];
    const float* internal = (const float*)d_in[1];
    const float* w_ih     = (const float*)d_in[2];
    const float* w_hh     = (const float*)d_in[3];
    const float* b_ih     = (const float*)d_in[4];
    const float* b_hh     = (const float*)d_in[5];
    const float* h0       = (const float*)d_in[6];
    float* out = (float*)d_out;

    // ws: w_hh_bf [4M us] | w_ih_bf [2M us] | h_bf[2][64][2048] | flags[64]
    unsigned short* w_hh_bf = (unsigned short*)d_ws;
    unsigned short* w_ih_bf = w_hh_bf + (size_t)Hh * Hh;
    unsigned short* h_bf    = w_ih_bf + (size_t)Hh * Ii;
    unsigned int*   flags   = (unsigned int*)(h_bf + (size_t)2 * Bb * Hh);

    hipLaunchKernelGGL(init_flags, dim3(1), dim3(NBLK), 0, stream, flags);
    hipLaunchKernelGGL(cvt_kernel, dim3((Hh * Hh) / 1024), dim3(256), 0, stream,
                       w_hh, w_hh_bf);
    hipLaunchKernelGGL(cvt_kernel, dim3((Hh * Ii) / 1024), dim3(256), 0, stream,
                       w_ih, w_ih_bf);
    hipLaunchKernelGGL(cvt_kernel, dim3((Bb * Hh) / 1024), dim3(256), 0, stream,
                       h0, h_bf);

    dim3 g1(Hh / 128, (Bb * Tt) / 128);
    hipLaunchKernelGGL(xproj_kernel, g1, dim3(256), 0, stream,
                       input, w_ih_bf, b_ih, out);

    void* args[] = {(void*)&w_hh_bf, (void*)&h_bf, (void*)&b_hh,
                    (void*)&internal, (void*)&out, (void*)&flags};
    hipLaunchCooperativeKernel((void*)rnn_persistent, dim3(NBLK), dim3(512),
                               args, 0, stream);
}

// Round 9
// 5121.248 us; speedup vs baseline: 2.4947x; 1.0581x over previous
//
#include <hip/hip_runtime.h>
#include <hip/hip_bf16.h>
#include <math.h>

#define Bb 64
#define Tt 512
#define Ii 1024
#define Hh 2048
#define NBLK 128

typedef __attribute__((ext_vector_type(8))) short bf16x8;
typedef __attribute__((ext_vector_type(8))) unsigned short ushort8;
typedef __attribute__((ext_vector_type(4))) float f32x4;

__device__ __forceinline__ unsigned short f2bf(float x) {
    unsigned int u = __float_as_uint(x);
    unsigned int r = u + 0x7fffu + ((u >> 16) & 1u);
    return (unsigned short)(r >> 16);
}

// ---------------------------------------------------------------------------
__global__ __launch_bounds__(256) void cvt_kernel(
    const float* __restrict__ src, unsigned short* __restrict__ dst)
{
    const int i = (blockIdx.x * 256 + threadIdx.x) * 4;
    float4 v = *(const float4*)(src + i);
    ushort4 o;
    o.x = f2bf(v.x); o.y = f2bf(v.y); o.z = f2bf(v.z); o.w = f2bf(v.w);
    *(ushort4*)(dst + i) = o;
}

__global__ void init_flags(unsigned int* flags) { flags[threadIdx.x] = 0u; }

// ---------------------------------------------------------------------------
// xproj: out[M=B*T][N=H] = input[M][K=I] @ w_ih^T + b_ih   (bf16 MFMA)
// ---------------------------------------------------------------------------
__global__ __launch_bounds__(256, 2) void xproj_kernel(
    const float* __restrict__ A,
    const unsigned short* __restrict__ Wbf,
    const float* __restrict__ bias,
    float* __restrict__ out)
{
    __shared__ unsigned short As[128 * 40];
    __shared__ unsigned short Bs[128 * 40];

    const int tid  = threadIdx.x;
    const int lane = tid & 63;
    const int wid  = tid >> 6;
    const int wm   = wid & 1;
    const int wn   = wid >> 1;
    const int rlo  = lane & 15;
    const int khi  = lane >> 4;

    const int m0 = blockIdx.y * 128;
    const int n0 = blockIdx.x * 128;

    f32x4 acc[4][4];
    #pragma unroll
    for (int i = 0; i < 4; ++i)
        #pragma unroll
        for (int j = 0; j < 4; ++j) acc[i][j] = (f32x4)0.f;

    for (int k0 = 0; k0 < Ii; k0 += 32) {
        #pragma unroll
        for (int p = 0; p < 4; ++p) {
            const int flat = p * 256 + tid;
            const int row  = flat >> 3;
            const int c4   = flat & 7;
            float4 v = *(const float4*)(A + (size_t)(m0 + row) * Ii + k0 + c4 * 4);
            ushort4 o;
            o.x = f2bf(v.x); o.y = f2bf(v.y); o.z = f2bf(v.z); o.w = f2bf(v.w);
            *(ushort4*)(As + row * 40 + c4 * 4) = o;
        }
        #pragma unroll
        for (int p = 0; p < 2; ++p) {
            const int flat = p * 256 + tid;
            const int row  = flat >> 2;
            const int c8   = flat & 3;
            ushort8 v = *(const ushort8*)(Wbf + (size_t)(n0 + row) * Ii + k0 + c8 * 8);
            *(ushort8*)(Bs + row * 40 + c8 * 8) = v;
        }
        __syncthreads();

        bf16x8 af[4], bfr[4];
        #pragma unroll
        for (int i = 0; i < 4; ++i)
            af[i] = *(const bf16x8*)(As + (wm * 64 + i * 16 + rlo) * 40 + khi * 8);
        #pragma unroll
        for (int j = 0; j < 4; ++j)
            bfr[j] = *(const bf16x8*)(Bs + (wn * 64 + j * 16 + rlo) * 40 + khi * 8);
        #pragma unroll
        for (int i = 0; i < 4; ++i)
            #pragma unroll
            for (int j = 0; j < 4; ++j)
                acc[i][j] = __builtin_amdgcn_mfma_f32_16x16x32_bf16(
                    af[i], bfr[j], acc[i][j], 0, 0, 0);
        __syncthreads();
    }

    #pragma unroll
    for (int j = 0; j < 4; ++j) {
        const int col = n0 + wn * 64 + j * 16 + rlo;
        const float bj = bias[col];
        #pragma unroll
        for (int i = 0; i < 4; ++i) {
            #pragma unroll
            for (int r = 0; r < 4; ++r) {
                const int m = m0 + wm * 64 + i * 16 + khi * 4 + r;
                out[(size_t)m * Hh + col] = acc[i][j][r] + bj;
            }
        }
    }
}

// ---------------------------------------------------------------------------
// asm helpers: system-scope (L2-bypassing) 16B load; drain-based waits only.
// ---------------------------------------------------------------------------
#define LD_FRAG(dst, base, OFF)                                               \
    asm volatile("global_load_dwordx4 %0, %1, off offset:" OFF " sc0 sc1"     \
                 : "=v"(dst) : "v"(base))

#define DRAIN16(a)                                                            \
    asm volatile("s_waitcnt vmcnt(0)"                                         \
                 : "+v"(a[0][0]), "+v"(a[0][1]), "+v"(a[0][2]), "+v"(a[0][3]),\
                   "+v"(a[0][4]), "+v"(a[0][5]), "+v"(a[0][6]), "+v"(a[0][7]),\
                   "+v"(a[1][0]), "+v"(a[1][1]), "+v"(a[1][2]), "+v"(a[1][3]),\
                   "+v"(a[1][4]), "+v"(a[1][5]), "+v"(a[1][6]), "+v"(a[1][7]) \
                 :: "memory");                                                \
    __builtin_amdgcn_sched_barrier(0)

// ---------------------------------------------------------------------------
// Persistent recurrence: 128 WGs x 512 thr (8 waves).
// WG = (rh in 0..1 -> 32 batch rows) x (cg in 0..63 -> 32 cols).
// Wave wid = K-slice [wid*256, +256). Per wave: 16 frags, ONE drain, 32 MFMA.
// Per-step VMEM order: h loads -> deferred out[t-1] stores -> xp[t] loads ->
// single vmcnt(0) -> MFMA -> reduce -> epilogue (waves 0-3) -> h stores ->
// short drain -> flag -> poll (first iteration waits only the flag load).
// ---------------------------------------------------------------------------
__global__ __launch_bounds__(512, 1) void rnn_persistent(
    const unsigned short* __restrict__ w_bf,   // [2048][2048] bf16
    unsigned short* __restrict__ h_bf,         // [2][64][2048] bf16 ping-pong
    const float* __restrict__ b_hh,            // [2048]
    const float* __restrict__ internal,        // [64][512]
    float* __restrict__ out,                   // [B][T][H] ++ [B][H]
    unsigned int* __restrict__ flags)          // [NBLK] arrival flags (zeroed)
{
    __shared__ f32x4 red4[8 * 256];            // 32 KiB

    const int tid  = threadIdx.x;
    const int lane = tid & 63;
    const int wid  = tid >> 6;                 // K-slice 0..7
    const int rlo  = lane & 15;
    const int khi  = lane >> 4;
    const int blk  = blockIdx.x;
    const int rh   = blk & 1;                  // row half: rows rh*32..+31
    const int cg   = blk >> 1;                 // col group: cols cg*32..+31

    // ---- preload w_hh slice into registers (lives for all 512 steps)
    bf16x8 wf[2][8];
    #pragma unroll
    for (int nt = 0; nt < 2; ++nt) {
        const unsigned short* wrow =
            w_bf + (size_t)(cg * 32 + nt * 16 + rlo) * Hh + wid * 256 + khi * 8;
        #pragma unroll
        for (int kit = 0; kit < 8; ++kit)
            wf[nt][kit] = *(const bf16x8*)(wrow + kit * 32);
    }

    // ---- epilogue decode (waves 0-3 only; round-8 verified col-pair mapping)
    // cell = tid (0..255): lane=cell&63, m=(cell>>6)&1, nt=cell>>7
    const int em    = (tid >> 6) & 1;
    const int ent   = (tid >> 7) & 1;          // valid for tid<256
    const int odd   = lane & 1;
    const int clloc = (ent * 16 + rlo) & ~1;
    const int cl    = cg * 32 + clloc;         // even col of the pair
    const int rAl   = em * 16 + khi * 4 + 2 * odd;
    const int rAg   = rh * 32 + rAl;           // global batch row A
    const int rBg   = rAg + 1;                 // global batch row B
    const float2 bh2 = (tid < 256) ? *(const float2*)(b_hh + cl)
                                   : make_float2(0.f, 0.f);

    // deferred out-store state (valid when t>0, tid<256)
    float2 gA_d = make_float2(0.f, 0.f), gB_d = make_float2(0.f, 0.f);

    for (int t = 0; t < Tt; ++t) {
        const bool last = (t == Tt - 1);
        const unsigned short* h_cur = h_bf + (size_t)(t & 1) * Bb * Hh;
        unsigned short*       h_nxt = h_bf + (size_t)((t + 1) & 1) * Bb * Hh;

        // ---- (a) issue h-fragment loads first (longest latency)
        const unsigned short* am0 =
            h_cur + (size_t)(rh * 32 + rlo) * Hh + wid * 256 + khi * 8;
        const unsigned short* am1 = am0 + (size_t)16 * Hh;

        bf16x8 a[2][8];
        LD_FRAG(a[0][0], am0, "0");   LD_FRAG(a[0][1], am0, "64");
        LD_FRAG(a[0][2], am0, "128"); LD_FRAG(a[0][3], am0, "192");
        LD_FRAG(a[0][4], am0, "256"); LD_FRAG(a[0][5], am0, "320");
        LD_FRAG(a[0][6], am0, "384"); LD_FRAG(a[0][7], am0, "448");
        LD_FRAG(a[1][0], am1, "0");   LD_FRAG(a[1][1], am1, "64");
        LD_FRAG(a[1][2], am1, "128"); LD_FRAG(a[1][3], am1, "192");
        LD_FRAG(a[1][4], am1, "256"); LD_FRAG(a[1][5], am1, "320");
        LD_FRAG(a[1][6], am1, "384"); LD_FRAG(a[1][7], am1, "448");

        // ---- (b) deferred out[t-1] stores + (c) xp/nz[t] loads ride the drain
        float2 xpA = make_float2(0.f, 0.f), xpB = make_float2(0.f, 0.f);
        float  nzA = 0.f, nzB = 0.f;
        if (tid < 256) {
            if (t > 0) {
                *(float2*)(out + ((size_t)rAg * Tt + (t - 1)) * Hh + cl) = gA_d;
                *(float2*)(out + ((size_t)rBg * Tt + (t - 1)) * Hh + cl) = gB_d;
            }
            xpA = *(const float2*)(out + ((size_t)rAg * Tt + t) * Hh + cl);
            xpB = *(const float2*)(out + ((size_t)rBg * Tt + t) * Hh + cl);
            nzA = internal[rAg * Tt + t];
            nzB = internal[rBg * Tt + t];
        }

        // ---- (d) single drain releases everything
        DRAIN16(a);

        // ---- (e) MFMA: 2 mtiles x 2 ntiles x 8 kits
        f32x4 acc[2][2];
        #pragma unroll
        for (int m = 0; m < 2; ++m)
            #pragma unroll
            for (int nt = 0; nt < 2; ++nt) acc[m][nt] = (f32x4)0.f;
        #pragma unroll
        for (int kk = 0; kk < 8; ++kk)
            #pragma unroll
            for (int m = 0; m < 2; ++m)
                #pragma unroll
                for (int nt = 0; nt < 2; ++nt)
                    acc[m][nt] = __builtin_amdgcn_mfma_f32_16x16x32_bf16(
                        a[m][kk], wf[nt][kk], acc[m][nt], 0, 0, 0);

        // ---- (f) 8-way k-split reduce
        #pragma unroll
        for (int nt = 0; nt < 2; ++nt)
            #pragma unroll
            for (int m = 0; m < 2; ++m)
                red4[wid * 256 + (nt * 2 + m) * 64 + lane] = acc[m][nt];
        __syncthreads();

        // ---- (g) epilogue: waves 0-3
        if (tid < 256) {
            f32x4 s4 = (f32x4)0.f;
            #pragma unroll
            for (int ks = 0; ks < 8; ++ks)
                s4 += red4[ks * 256 + tid];

            f32x4 o4;
            #pragma unroll
            for (int i = 0; i < 4; ++i)
                o4[i] = __shfl_xor(s4[i], 1, 64);

            const float sA_lo = odd ? o4[2] : s4[0];
            const float sA_hi = odd ? s4[2] : o4[0];
            const float sB_lo = odd ? o4[3] : s4[1];
            const float sB_hi = odd ? s4[3] : o4[1];

            float2 gA, gB;
            gA.x = tanhf(xpA.x + nzA + bh2.x + sA_lo);
            gA.y = tanhf(xpA.y + nzA + bh2.y + sA_hi);
            gB.x = tanhf(xpB.x + nzB + bh2.x + sB_lo);
            gB.y = tanhf(xpB.y + nzB + bh2.y + sB_hi);

            // ---- (h) h_nxt stores (agent scope, write-through)
            const unsigned int hpA =
                (unsigned int)f2bf(gA.x) | ((unsigned int)f2bf(gA.y) << 16);
            const unsigned int hpB =
                (unsigned int)f2bf(gB.x) | ((unsigned int)f2bf(gB.y) << 16);
            __hip_atomic_store((unsigned int*)h_nxt + ((size_t)rAg * Hh + cl) / 2,
                               hpA, __ATOMIC_RELAXED, __HIP_MEMORY_SCOPE_AGENT);
            __hip_atomic_store((unsigned int*)h_nxt + ((size_t)rBg * Hh + cl) / 2,
                               hpB, __ATOMIC_RELAXED, __HIP_MEMORY_SCOPE_AGENT);

            if (last) {
                // final step: store out + tail directly (no deferral)
                *(float2*)(out + ((size_t)rAg * Tt + t) * Hh + cl) = gA;
                *(float2*)(out + ((size_t)rBg * Tt + t) * Hh + cl) = gB;
                float* tail = out + (size_t)Bb * Tt * Hh;
                *(float2*)(tail + (size_t)rAg * Hh + cl) = gA;
                *(float2*)(tail + (size_t)rBg * Hh + cl) = gB;
            } else {
                gA_d = gA; gB_d = gB;      // defer to next iteration
            }
        }
        if (last) break;

        // ---- (i) drain h stores (only h outstanding for epilogue threads)
        asm volatile("s_waitcnt vmcnt(0)" ::: "memory");
        __syncthreads();                   // all threads' h stores drained

        // ---- (j) arrive
        if (tid == 0)
            __hip_atomic_store(flags + blk, (unsigned int)(t + 1),
                               __ATOMIC_RELAXED, __HIP_MEMORY_SCOPE_AGENT);

        // ---- (k) poll: waves 0-1 cover the 128 flags
        if (wid < 2) {
            const unsigned int tgt = (unsigned int)(t + 1);
            while (true) {
                unsigned int f = __hip_atomic_load(
                    flags + wid * 64 + lane, __ATOMIC_RELAXED,
                    __HIP_MEMORY_SCOPE_AGENT);
                if (__all(f >= tgt)) break;
            }
        }
        __syncthreads();
    }
}

// ---------------------------------------------------------------------------
extern "C" void kernel_launch(void* const* d_in, const int* in_sizes, int n_in,
                              void* d_out, int out_size, void* d_ws, size_t ws_size,
                              hipStream_t stream) {
    const float* input    = (const float*)d_in[0];
    const float* internal = (const float*)d_in[1];
    const float* w_ih     = (const float*)d_in[2];
    const float* w_hh     = (const float*)d_in[3];
    const float* b_ih     = (const float*)d_in[4];
    const float* b_hh     = (const float*)d_in[5];
    const float* h0       = (const float*)d_in[6];
    float* out = (float*)d_out;

    // ws: w_hh_bf [4M us] | w_ih_bf [2M us] | h_bf[2][64][2048] | flags[128]
    unsigned short* w_hh_bf = (unsigned short*)d_ws;
    unsigned short* w_ih_bf = w_hh_bf + (size_t)Hh * Hh;
    unsigned short* h_bf    = w_ih_bf + (size_t)Hh * Ii;
    unsigned int*   flags   = (unsigned int*)(h_bf + (size_t)2 * Bb * Hh);

    hipLaunchKernelGGL(init_flags, dim3(1), dim3(NBLK), 0, stream, flags);
    hipLaunchKernelGGL(cvt_kernel, dim3((Hh * Hh) / 1024), dim3(256), 0, stream,
                       w_hh, w_hh_bf);
    hipLaunchKernelGGL(cvt_kernel, dim3((Hh * Ii) / 1024), dim3(256), 0, stream,
                       w_ih, w_ih_bf);
    hipLaunchKernelGGL(cvt_kernel, dim3((Bb * Hh) / 1024), dim3(256), 0, stream,
                       h0, h_bf);

    dim3 g1(Hh / 128, (Bb * Tt) / 128);
    hipLaunchKernelGGL(xproj_kernel, g1, dim3(256), 0, stream,
                       input, w_ih_bf, b_ih, out);

    void* args[] = {(void*)&w_hh_bf, (void*)&h_bf, (void*)&b_hh,
                    (void*)&internal, (void*)&out, (void*)&flags};
    hipLaunchCooperativeKernel((void*)rnn_persistent, dim3(NBLK), dim3(512),
                               args, 0, stream);
}

// Round 10
// 4045.276 us; speedup vs baseline: 3.1582x; 1.2660x over previous
//
#include <hip/hip_runtime.h>
#include <hip/hip_bf16.h>
#include <math.h>

#define Bb 64
#define Tt 512
#define Ii 1024
#define Hh 2048
#define NBLK 128

typedef __attribute__((ext_vector_type(8))) short bf16x8;
typedef __attribute__((ext_vector_type(8))) unsigned short ushort8;
typedef __attribute__((ext_vector_type(4))) float f32x4;

__device__ __forceinline__ unsigned short f2bf(float x) {
    unsigned int u = __float_as_uint(x);
    unsigned int r = u + 0x7fffu + ((u >> 16) & 1u);
    return (unsigned short)(r >> 16);
}

// ---------------------------------------------------------------------------
__global__ __launch_bounds__(256) void cvt_kernel(
    const float* __restrict__ src, unsigned short* __restrict__ dst)
{
    const int i = (blockIdx.x * 256 + threadIdx.x) * 4;
    float4 v = *(const float4*)(src + i);
    ushort4 o;
    o.x = f2bf(v.x); o.y = f2bf(v.y); o.z = f2bf(v.z); o.w = f2bf(v.w);
    *(ushort4*)(dst + i) = o;
}

__global__ void init_flags(unsigned int* flags) {
    if (threadIdx.x <= NBLK) flags[threadIdx.x] = 0u;   // 128 flags + root
}

// ---------------------------------------------------------------------------
// xproj: out[M=B*T][N=H] = input[M][K=I] @ w_ih^T + b_ih   (bf16 MFMA)
// ---------------------------------------------------------------------------
__global__ __launch_bounds__(256, 2) void xproj_kernel(
    const float* __restrict__ A,
    const unsigned short* __restrict__ Wbf,
    const float* __restrict__ bias,
    float* __restrict__ out)
{
    __shared__ unsigned short As[128 * 40];
    __shared__ unsigned short Bs[128 * 40];

    const int tid  = threadIdx.x;
    const int lane = tid & 63;
    const int wid  = tid >> 6;
    const int wm   = wid & 1;
    const int wn   = wid >> 1;
    const int rlo  = lane & 15;
    const int khi  = lane >> 4;

    const int m0 = blockIdx.y * 128;
    const int n0 = blockIdx.x * 128;

    f32x4 acc[4][4];
    #pragma unroll
    for (int i = 0; i < 4; ++i)
        #pragma unroll
        for (int j = 0; j < 4; ++j) acc[i][j] = (f32x4)0.f;

    for (int k0 = 0; k0 < Ii; k0 += 32) {
        #pragma unroll
        for (int p = 0; p < 4; ++p) {
            const int flat = p * 256 + tid;
            const int row  = flat >> 3;
            const int c4   = flat & 7;
            float4 v = *(const float4*)(A + (size_t)(m0 + row) * Ii + k0 + c4 * 4);
            ushort4 o;
            o.x = f2bf(v.x); o.y = f2bf(v.y); o.z = f2bf(v.z); o.w = f2bf(v.w);
            *(ushort4*)(As + row * 40 + c4 * 4) = o;
        }
        #pragma unroll
        for (int p = 0; p < 2; ++p) {
            const int flat = p * 256 + tid;
            const int row  = flat >> 2;
            const int c8   = flat & 3;
            ushort8 v = *(const ushort8*)(Wbf + (size_t)(n0 + row) * Ii + k0 + c8 * 8);
            *(ushort8*)(Bs + row * 40 + c8 * 8) = v;
        }
        __syncthreads();

        bf16x8 af[4], bfr[4];
        #pragma unroll
        for (int i = 0; i < 4; ++i)
            af[i] = *(const bf16x8*)(As + (wm * 64 + i * 16 + rlo) * 40 + khi * 8);
        #pragma unroll
        for (int j = 0; j < 4; ++j)
            bfr[j] = *(const bf16x8*)(Bs + (wn * 64 + j * 16 + rlo) * 40 + khi * 8);
        #pragma unroll
        for (int i = 0; i < 4; ++i)
            #pragma unroll
            for (int j = 0; j < 4; ++j)
                acc[i][j] = __builtin_amdgcn_mfma_f32_16x16x32_bf16(
                    af[i], bfr[j], acc[i][j], 0, 0, 0);
        __syncthreads();
    }

    #pragma unroll
    for (int j = 0; j < 4; ++j) {
        const int col = n0 + wn * 64 + j * 16 + rlo;
        const float bj = bias[col];
        #pragma unroll
        for (int i = 0; i < 4; ++i) {
            #pragma unroll
            for (int r = 0; r < 4; ++r) {
                const int m = m0 + wm * 64 + i * 16 + khi * 4 + r;
                out[(size_t)m * Hh + col] = acc[i][j][r] + bj;
            }
        }
    }
}

// ---------------------------------------------------------------------------
// asm helpers
// ---------------------------------------------------------------------------
#define LD_FRAG(dst, base, OFF)                                               \
    asm volatile("global_load_dwordx4 %0, %1, off offset:" OFF " sc0 sc1"     \
                 : "=v"(dst) : "v"(base))

#define DRAIN16(a)                                                            \
    asm volatile("s_waitcnt vmcnt(0)"                                         \
                 : "+v"(a[0][0]), "+v"(a[0][1]), "+v"(a[0][2]), "+v"(a[0][3]),\
                   "+v"(a[0][4]), "+v"(a[0][5]), "+v"(a[0][6]), "+v"(a[0][7]),\
                   "+v"(a[1][0]), "+v"(a[1][1]), "+v"(a[1][2]), "+v"(a[1][3]),\
                   "+v"(a[1][4]), "+v"(a[1][5]), "+v"(a[1][6]), "+v"(a[1][7]) \
                 :: "memory");                                                \
    __builtin_amdgcn_sched_barrier(0)

// Raw barrier: LDS-safe (lgkm drained) but does NOT drain vmcnt, so
// in-flight global prefetches survive the barrier.
#define RAW_BARRIER()                                                         \
    asm volatile("s_waitcnt lgkmcnt(0)\n\ts_barrier" ::: "memory")

// ---------------------------------------------------------------------------
// Persistent recurrence: 128 WGs x 512 thr (8 waves).
// WG = (rh in 0..1 -> 32 batch rows) x (cg in 0..63 -> 32 cols).
// Wave wid = K-slice [wid*256, +256). Per wave: 16 frags, ONE drain, 32 MFMA.
// Barrier: per-WG flag stores -> single aggregator wave (blk0/wid7) -> root
// flag; everyone else polls root with one same-address load + s_sleep.
// Raw s_barrier everywhere (vmcnt survives); xp prefetch rides the barrier.
// ---------------------------------------------------------------------------
__global__ __launch_bounds__(512, 1) void rnn_persistent(
    const unsigned short* __restrict__ w_bf,   // [2048][2048] bf16
    unsigned short* __restrict__ h_bf,         // [2][64][2048] bf16 ping-pong
    const float* __restrict__ b_hh,            // [2048]
    const float* __restrict__ internal,        // [64][512]
    float* __restrict__ out,                   // [B][T][H] ++ [B][H]
    unsigned int* __restrict__ flags)          // [NBLK] flags + [1] root
{
    __shared__ f32x4 red4[8 * 256];            // 32 KiB

    const int tid  = threadIdx.x;
    const int lane = tid & 63;
    const int wid  = tid >> 6;                 // K-slice 0..7
    const int rlo  = lane & 15;
    const int khi  = lane >> 4;
    const int blk  = blockIdx.x;
    const int rh   = blk & 1;                  // row half: rows rh*32..+31
    const int cg   = blk >> 1;                 // col group: cols cg*32..+31
    unsigned int* root = flags + NBLK;

    // ---- preload w_hh slice into registers (lives for all 512 steps)
    bf16x8 wf[2][8];
    #pragma unroll
    for (int nt = 0; nt < 2; ++nt) {
        const unsigned short* wrow =
            w_bf + (size_t)(cg * 32 + nt * 16 + rlo) * Hh + wid * 256 + khi * 8;
        #pragma unroll
        for (int kit = 0; kit < 8; ++kit)
            wf[nt][kit] = *(const bf16x8*)(wrow + kit * 32);
    }

    // ---- epilogue decode (round-9 verified)
    const int em    = (tid >> 6) & 1;
    const int ent   = (tid >> 7) & 1;          // valid for tid<256
    const int odd   = lane & 1;
    const int clloc = (ent * 16 + rlo) & ~1;
    const int cl    = cg * 32 + clloc;         // even col of the pair
    const int rAl   = em * 16 + khi * 4 + 2 * odd;
    const int rAg   = rh * 32 + rAl;           // global batch row A
    const int rBg   = rAg + 1;                 // global batch row B
    const float2 bh2 = (tid < 256) ? *(const float2*)(b_hh + cl)
                                   : make_float2(0.f, 0.f);

    // epilogue operands for t=0 (prologue); prefetched ahead inside the loop
    float2 xpA = make_float2(0.f, 0.f), xpB = make_float2(0.f, 0.f);
    float  nzA = 0.f, nzB = 0.f;
    if (tid < 256) {
        xpA = *(const float2*)(out + ((size_t)rAg * Tt + 0) * Hh + cl);
        xpB = *(const float2*)(out + ((size_t)rBg * Tt + 0) * Hh + cl);
        nzA = internal[rAg * Tt + 0];
        nzB = internal[rBg * Tt + 0];
    }
    float2 gA_d = make_float2(0.f, 0.f), gB_d = make_float2(0.f, 0.f);

    for (int t = 0; t < Tt; ++t) {
        const bool last = (t == Tt - 1);
        const unsigned short* h_cur = h_bf + (size_t)(t & 1) * Bb * Hh;
        unsigned short*       h_nxt = h_bf + (size_t)((t + 1) & 1) * Bb * Hh;

        // ---- (a) issue h-fragment loads first (longest latency)
        const unsigned short* am0 =
            h_cur + (size_t)(rh * 32 + rlo) * Hh + wid * 256 + khi * 8;
        const unsigned short* am1 = am0 + (size_t)16 * Hh;

        bf16x8 a[2][8];
        LD_FRAG(a[0][0], am0, "0");   LD_FRAG(a[0][1], am0, "64");
        LD_FRAG(a[0][2], am0, "128"); LD_FRAG(a[0][3], am0, "192");
        LD_FRAG(a[0][4], am0, "256"); LD_FRAG(a[0][5], am0, "320");
        LD_FRAG(a[0][6], am0, "384"); LD_FRAG(a[0][7], am0, "448");
        LD_FRAG(a[1][0], am1, "0");   LD_FRAG(a[1][1], am1, "64");
        LD_FRAG(a[1][2], am1, "128"); LD_FRAG(a[1][3], am1, "192");
        LD_FRAG(a[1][4], am1, "256"); LD_FRAG(a[1][5], am1, "320");
        LD_FRAG(a[1][6], am1, "384"); LD_FRAG(a[1][7], am1, "448");

        // ---- (b) deferred out[t-1] stores ride the same drain
        if (tid < 256 && t > 0) {
            *(float2*)(out + ((size_t)rAg * Tt + (t - 1)) * Hh + cl) = gA_d;
            *(float2*)(out + ((size_t)rBg * Tt + (t - 1)) * Hh + cl) = gB_d;
        }

        // ---- (d) single drain releases everything (incl. xp prefetches)
        DRAIN16(a);

        // ---- (e) MFMA: 2 mtiles x 2 ntiles x 8 kits
        f32x4 acc[2][2];
        #pragma unroll
        for (int m = 0; m < 2; ++m)
            #pragma unroll
            for (int nt = 0; nt < 2; ++nt) acc[m][nt] = (f32x4)0.f;
        #pragma unroll
        for (int kk = 0; kk < 8; ++kk)
            #pragma unroll
            for (int m = 0; m < 2; ++m)
                #pragma unroll
                for (int nt = 0; nt < 2; ++nt)
                    acc[m][nt] = __builtin_amdgcn_mfma_f32_16x16x32_bf16(
                        a[m][kk], wf[nt][kk], acc[m][nt], 0, 0, 0);

        // ---- (f) 8-way k-split reduce (raw barrier: LDS only)
        #pragma unroll
        for (int nt = 0; nt < 2; ++nt)
            #pragma unroll
            for (int m = 0; m < 2; ++m)
                red4[wid * 256 + (nt * 2 + m) * 64 + lane] = acc[m][nt];
        RAW_BARRIER();

        // ---- (g) epilogue: waves 0-3
        if (tid < 256) {
            f32x4 s4 = (f32x4)0.f;
            #pragma unroll
            for (int ks = 0; ks < 8; ++ks)
                s4 += red4[ks * 256 + tid];

            f32x4 o4;
            #pragma unroll
            for (int i = 0; i < 4; ++i)
                o4[i] = __shfl_xor(s4[i], 1, 64);

            const float sA_lo = odd ? o4[2] : s4[0];
            const float sA_hi = odd ? s4[2] : o4[0];
            const float sB_lo = odd ? o4[3] : s4[1];
            const float sB_hi = odd ? s4[3] : o4[1];

            float2 gA, gB;
            gA.x = tanhf(xpA.x + nzA + bh2.x + sA_lo);
            gA.y = tanhf(xpA.y + nzA + bh2.y + sA_hi);
            gB.x = tanhf(xpB.x + nzB + bh2.x + sB_lo);
            gB.y = tanhf(xpB.y + nzB + bh2.y + sB_hi);

            const unsigned int hpA =
                (unsigned int)f2bf(gA.x) | ((unsigned int)f2bf(gA.y) << 16);
            const unsigned int hpB =
                (unsigned int)f2bf(gB.x) | ((unsigned int)f2bf(gB.y) << 16);
            __hip_atomic_store((unsigned int*)h_nxt + ((size_t)rAg * Hh + cl) / 2,
                               hpA, __ATOMIC_RELAXED, __HIP_MEMORY_SCOPE_AGENT);
            __hip_atomic_store((unsigned int*)h_nxt + ((size_t)rBg * Hh + cl) / 2,
                               hpB, __ATOMIC_RELAXED, __HIP_MEMORY_SCOPE_AGENT);

            if (last) {
                *(float2*)(out + ((size_t)rAg * Tt + t) * Hh + cl) = gA;
                *(float2*)(out + ((size_t)rBg * Tt + t) * Hh + cl) = gB;
                float* tail = out + (size_t)Bb * Tt * Hh;
                *(float2*)(tail + (size_t)rAg * Hh + cl) = gA;
                *(float2*)(tail + (size_t)rBg * Hh + cl) = gB;
            } else {
                gA_d = gA; gB_d = gB;      // defer to next iteration
            }
        }
        if (last) break;

        // ---- (i) per-wave drain of h stores (only h outstanding here)
        asm volatile("s_waitcnt vmcnt(0)" ::: "memory");

        // ---- xp/nz prefetch for t+1: issued now, rides the barrier wait,
        //      drained by next step's DRAIN16.
        if (tid < 256) {
            xpA = *(const float2*)(out + ((size_t)rAg * Tt + t + 1) * Hh + cl);
            xpB = *(const float2*)(out + ((size_t)rBg * Tt + t + 1) * Hh + cl);
            nzA = internal[rAg * Tt + t + 1];
            nzB = internal[rBg * Tt + t + 1];
        }

        RAW_BARRIER();                     // all waves' h stores drained

        // ---- arrive: one flag store per WG
        if (tid == 0)
            __hip_atomic_store(flags + blk, (unsigned int)(t + 1),
                               __ATOMIC_RELAXED, __HIP_MEMORY_SCOPE_AGENT);

        // ---- tree barrier
        const unsigned int tgt = (unsigned int)(t + 1);
        if (blk == 0 && wid == 7) {
            // aggregator: poll all 128 flags, then publish root
            while (true) {
                unsigned int f0 = __hip_atomic_load(
                    flags + lane, __ATOMIC_RELAXED, __HIP_MEMORY_SCOPE_AGENT);
                unsigned int f1 = __hip_atomic_load(
                    flags + 64 + lane, __ATOMIC_RELAXED, __HIP_MEMORY_SCOPE_AGENT);
                if (__all((f0 >= tgt) && (f1 >= tgt))) break;
                __builtin_amdgcn_s_sleep(1);
            }
            if (lane == 0)
                __hip_atomic_store(root, tgt, __ATOMIC_RELAXED,
                                   __HIP_MEMORY_SCOPE_AGENT);
        } else if (wid == 7) {
            // everyone else: poll the single root flag
            while (__hip_atomic_load(root, __ATOMIC_RELAXED,
                                     __HIP_MEMORY_SCOPE_AGENT) < tgt)
                __builtin_amdgcn_s_sleep(1);
        }
        RAW_BARRIER();                     // release: root seen by wave 7
    }
}

// ---------------------------------------------------------------------------
extern "C" void kernel_launch(void* const* d_in, const int* in_sizes, int n_in,
                              void* d_out, int out_size, void* d_ws, size_t ws_size,
                              hipStream_t stream) {
    const float* input    = (const float*)d_in[0];
    const float* internal = (const float*)d_in[1];
    const float* w_ih     = (const float*)d_in[2];
    const float* w_hh     = (const float*)d_in[3];
    const float* b_ih     = (const float*)d_in[4];
    const float* b_hh     = (const float*)d_in[5];
    const float* h0       = (const float*)d_in[6];
    float* out = (float*)d_out;

    // ws: w_hh_bf [4M us] | w_ih_bf [2M us] | h_bf[2][64][2048] | flags[129]
    unsigned short* w_hh_bf = (unsigned short*)d_ws;
    unsigned short* w_ih_bf = w_hh_bf + (size_t)Hh * Hh;
    unsigned short* h_bf    = w_ih_bf + (size_t)Hh * Ii;
    unsigned int*   flags   = (unsigned int*)(h_bf + (size_t)2 * Bb * Hh);

    hipLaunchKernelGGL(init_flags, dim3(1), dim3(256), 0, stream, flags);
    hipLaunchKernelGGL(cvt_kernel, dim3((Hh * Hh) / 1024), dim3(256), 0, stream,
                       w_hh, w_hh_bf);
    hipLaunchKernelGGL(cvt_kernel, dim3((Hh * Ii) / 1024), dim3(256), 0, stream,
                       w_ih, w_ih_bf);
    hipLaunchKernelGGL(cvt_kernel, dim3((Bb * Hh) / 1024), dim3(256), 0, stream,
                       h0, h_bf);

    dim3 g1(Hh / 128, (Bb * Tt) / 128);
    hipLaunchKernelGGL(xproj_kernel, g1, dim3(256), 0, stream,
                       input, w_ih_bf, b_ih, out);

    void* args[] = {(void*)&w_hh_bf, (void*)&h_bf, (void*)&b_hh,
                    (void*)&internal, (void*)&out, (void*)&flags};
    hipLaunchCooperativeKernel((void*)rnn_persistent, dim3(NBLK), dim3(512),
                               args, 0, stream);
}